// Round 4
// baseline (584.036 us; speedup 1.0000x reference)
//
#include <hip/hip_runtime.h>

// ROUND 4: round-2 MFMA pipeline, OUTPUT AS FP32 (reference returns float32;
// the "bf16" in the harness label is baked text, not the executed decode path).
// Inputs fp32 (established: round-1 bf16 reads -> NaN).

#define NPATH 8192
#define LMAX  32
#define DIN   256
#define EDIM  128
#define HDIM  128
#define G4    512
#define NGRP  1024
#define NTOK  (NPATH * LMAX)   // 262144

typedef __attribute__((ext_vector_type(8))) short short8;
typedef __attribute__((ext_vector_type(4))) short s16x4;
typedef __attribute__((ext_vector_type(4))) float f32x4;

__device__ __forceinline__ unsigned short f2bf(float f) {
    unsigned int x = __float_as_uint(f);
    x += 0x7fffu + ((x >> 16) & 1u);   // RNE
    return (unsigned short)(x >> 16);
}
__device__ __forceinline__ float sigmoid_f(float x) {
    return __fdividef(1.f, 1.f + __expf(-x));
}
__device__ __forceinline__ float tanh_f(float x) {
    float ax = fabsf(x);
    float t = __expf(-2.f * ax);
    float r = __fdividef(1.f - t, 1.f + t);
    return copysignf(r, x);
}

// ---------------- K1: projection GEMM + LayerNorm + tanh -> x~ (bf16 ws) ----
#define K1_ROWS 128
#define K1_PAD  264   // 256 + 8 elems: 528B row stride, 16B aligned
__global__ __launch_bounds__(512) void k1_proj(
    const float* __restrict__ inp, const float* __restrict__ Win,
    const float* __restrict__ gam, const float* __restrict__ bet,
    unsigned short* __restrict__ xt)
{
    __shared__ short As[K1_ROWS * K1_PAD];  // 67584 B
    __shared__ short Bs[EDIM * K1_PAD];     // 67584 B
    const int tid = threadIdx.x;
    const long m0 = (long)blockIdx.x * K1_ROWS;

    #pragma unroll
    for (int i = 0; i < 16; ++i) {          // W_in: 128x256 fp32 = 8192 float4
        int chunk = i * 512 + tid;
        int row = chunk >> 6, c4 = chunk & 63;
        float4 v = *(const float4*)&Win[row * DIN + c4 * 4];
        s16x4 s = { (short)f2bf(v.x), (short)f2bf(v.y), (short)f2bf(v.z), (short)f2bf(v.w) };
        *(s16x4*)&Bs[row * K1_PAD + c4 * 4] = s;
    }
    #pragma unroll
    for (int i = 0; i < 16; ++i) {          // A-tile: 128x256 fp32
        int chunk = i * 512 + tid;
        int row = chunk >> 6, c4 = chunk & 63;
        float4 v = *(const float4*)&inp[(m0 + row) * DIN + c4 * 4];
        s16x4 s = { (short)f2bf(v.x), (short)f2bf(v.y), (short)f2bf(v.z), (short)f2bf(v.w) };
        *(s16x4*)&As[row * K1_PAD + c4 * 4] = s;
    }
    __syncthreads();

    const int w = tid >> 6, lane = tid & 63, q = lane >> 4, c = lane & 15;
    const f32x4 fzero = {0.f, 0.f, 0.f, 0.f};
    f32x4 acc[8];
    #pragma unroll
    for (int nt = 0; nt < 8; ++nt) acc[nt] = fzero;

    const short* arow = &As[(w * 16 + c) * K1_PAD + q * 8];
    const short* brow = &Bs[c * K1_PAD + q * 8];
    #pragma unroll
    for (int ks = 0; ks < 8; ++ks) {
        short8 a = *(const short8*)(arow + ks * 32);
        #pragma unroll
        for (int nt = 0; nt < 8; ++nt) {
            short8 b = *(const short8*)(brow + nt * 16 * K1_PAD + ks * 32);
            acc[nt] = __builtin_amdgcn_mfma_f32_16x16x32_bf16(a, b, acc[nt], 0, 0, 0);
        }
    }

    // LayerNorm per row (row = m0 + 16w + 4q + r), cols = 16*nt + c
    float gr[8], br[8];
    #pragma unroll
    for (int nt = 0; nt < 8; ++nt) { int col = nt * 16 + c; gr[nt] = gam[col]; br[nt] = bet[col]; }
    #pragma unroll
    for (int r = 0; r < 4; ++r) {
        float s = 0.f, ss = 0.f;
        #pragma unroll
        for (int nt = 0; nt < 8; ++nt) { float v = acc[nt][r]; s += v; ss += v * v; }
        #pragma unroll
        for (int m = 1; m < 16; m <<= 1) { s += __shfl_xor(s, m, 64); ss += __shfl_xor(ss, m, 64); }
        float mu = s * (1.f / 128.f);
        float var = ss * (1.f / 128.f) - mu * mu;
        float rstd = rsqrtf(var + 1e-5f);
        unsigned short* orow = &xt[(m0 + w * 16 + q * 4 + r) * EDIM];
        #pragma unroll
        for (int nt = 0; nt < 8; ++nt) {
            float v = (acc[nt][r] - mu) * rstd * gr[nt] + br[nt];
            orow[nt * 16 + c] = f2bf(tanh_f(v));
        }
    }
}

// ---------------- K2: persistent LSTM, 32 rows/block, 32 steps ---------------
#define K2_PAD 136    // 128 + 8: 272B row stride, 16B aligned
__global__ __launch_bounds__(512) void k2_lstm(
    const unsigned short* __restrict__ xt,
    const float* __restrict__ Wih, const float* __restrict__ Whh,
    const float* __restrict__ bih, const float* __restrict__ bhh,
    const int* __restrict__ lens, float* __restrict__ h_last)
{
    __shared__ short Wh[G4 * K2_PAD];   // 139264 B
    __shared__ short xb[32 * K2_PAD];   // 8704 B
    __shared__ short hb[32 * K2_PAD];   // 8704 B
    __shared__ int   lenb[32];
    const int tid = threadIdx.x;
    const int r0 = blockIdx.x * 32;

    #pragma unroll
    for (int i = 0; i < 32; ++i) {      // Whh 512x128 fp32 = 16384 float4
        int chunk = i * 512 + tid;
        int row = chunk >> 5, c4 = chunk & 31;
        float4 v = *(const float4*)&Whh[row * HDIM + c4 * 4];
        s16x4 s = { (short)f2bf(v.x), (short)f2bf(v.y), (short)f2bf(v.z), (short)f2bf(v.w) };
        *(s16x4*)&Wh[row * K2_PAD + c4 * 4] = s;
    }
    for (int idx = tid; idx < 32 * K2_PAD; idx += 512) hb[idx] = 0;
    if (tid < 32) lenb[tid] = lens[r0 + tid];
    __syncthreads();

    const int w = tid >> 6, lane = tid & 63, q = lane >> 4, c = lane & 15;
    float bs[4];
    #pragma unroll
    for (int g_ = 0; g_ < 4; ++g_) { int j = g_ * 128 + w * 16 + c; bs[g_] = bih[j] + bhh[j]; }
    int lenr[2][4];
    #pragma unroll
    for (int mt = 0; mt < 2; ++mt)
        #pragma unroll
        for (int r = 0; r < 4; ++r) lenr[mt][r] = lenb[mt * 16 + q * 4 + r];

    // Wih B-fragments: step-invariant, fp32->bf16 once into VGPRs
    short8 wf[4][4];
    #pragma unroll
    for (int g_ = 0; g_ < 4; ++g_) {
        const float* p = Wih + (g_ * 128 + w * 16 + c) * EDIM + q * 8;
        #pragma unroll
        for (int ks = 0; ks < 4; ++ks) {
            float4 u0 = *(const float4*)(p + ks * 32);
            float4 u1 = *(const float4*)(p + ks * 32 + 4);
            short8 s;
            s[0] = (short)f2bf(u0.x); s[1] = (short)f2bf(u0.y);
            s[2] = (short)f2bf(u0.z); s[3] = (short)f2bf(u0.w);
            s[4] = (short)f2bf(u1.x); s[5] = (short)f2bf(u1.y);
            s[6] = (short)f2bf(u1.z); s[7] = (short)f2bf(u1.w);
            wf[g_][ks] = s;
        }
    }
    const short* whb[4];
    #pragma unroll
    for (int g_ = 0; g_ < 4; ++g_) whb[g_] = &Wh[(g_ * 128 + w * 16 + c) * K2_PAD + q * 8];
    const short* xbb[2]; const short* hbb[2];
    #pragma unroll
    for (int mt = 0; mt < 2; ++mt) {
        xbb[mt] = &xb[(mt * 16 + c) * K2_PAD + q * 8];
        hbb[mt] = &hb[(mt * 16 + c) * K2_PAD + q * 8];
    }

    float c_reg[2][4] = {{0.f,0.f,0.f,0.f},{0.f,0.f,0.f,0.f}};
    float h_reg[2][4] = {{0.f,0.f,0.f,0.f},{0.f,0.f,0.f,0.f}};
    const f32x4 fzero = {0.f, 0.f, 0.f, 0.f};

    for (int t = 0; t < LMAX; ++t) {
        {   // stage x~[rows, t, :] (bf16) -> xb
            int row = tid >> 4, c8 = tid & 15;
            *(short8*)&xb[row * K2_PAD + c8 * 8] =
                *(const short8*)&xt[((long)(r0 + row) * LMAX + t) * EDIM + c8 * 8];
        }
        __syncthreads();   // xb ready; hb(t) ready

        f32x4 acc[2][4];
        #pragma unroll
        for (int mt = 0; mt < 2; ++mt)
            #pragma unroll
            for (int g_ = 0; g_ < 4; ++g_) acc[mt][g_] = fzero;

        #pragma unroll
        for (int ks = 0; ks < 4; ++ks) {   // recurrent: A=hb, B=Whh(LDS)
            short8 a0 = *(const short8*)(hbb[0] + ks * 32);
            short8 a1 = *(const short8*)(hbb[1] + ks * 32);
            #pragma unroll
            for (int g_ = 0; g_ < 4; ++g_) {
                short8 b = *(const short8*)(whb[g_] + ks * 32);
                acc[0][g_] = __builtin_amdgcn_mfma_f32_16x16x32_bf16(a0, b, acc[0][g_], 0, 0, 0);
                acc[1][g_] = __builtin_amdgcn_mfma_f32_16x16x32_bf16(a1, b, acc[1][g_], 0, 0, 0);
            }
        }
        #pragma unroll
        for (int ks = 0; ks < 4; ++ks) {   // input: A=xb, B=Wih(VGPR)
            short8 a0 = *(const short8*)(xbb[0] + ks * 32);
            short8 a1 = *(const short8*)(xbb[1] + ks * 32);
            #pragma unroll
            for (int g_ = 0; g_ < 4; ++g_) {
                acc[0][g_] = __builtin_amdgcn_mfma_f32_16x16x32_bf16(a0, wf[g_][ks], acc[0][g_], 0, 0, 0);
                acc[1][g_] = __builtin_amdgcn_mfma_f32_16x16x32_bf16(a1, wf[g_][ks], acc[1][g_], 0, 0, 0);
            }
        }

        #pragma unroll
        for (int mt = 0; mt < 2; ++mt)
            #pragma unroll
            for (int r = 0; r < 4; ++r) {
                float iv = acc[mt][0][r] + bs[0];
                float fv = acc[mt][1][r] + bs[1];
                float gv = acc[mt][2][r] + bs[2];
                float ov = acc[mt][3][r] + bs[3];
                float cn = sigmoid_f(fv) * c_reg[mt][r] + sigmoid_f(iv) * tanh_f(gv);
                float hn = sigmoid_f(ov) * tanh_f(cn);
                if (t < lenr[mt][r]) { c_reg[mt][r] = cn; h_reg[mt][r] = hn; }
            }
        __syncthreads();   // all waves done reading hb & xb
        #pragma unroll
        for (int mt = 0; mt < 2; ++mt)
            #pragma unroll
            for (int r = 0; r < 4; ++r)
                hb[(mt * 16 + q * 4 + r) * K2_PAD + w * 16 + c] = (short)f2bf(h_reg[mt][r]);
    }

    #pragma unroll
    for (int mt = 0; mt < 2; ++mt)
        #pragma unroll
        for (int r = 0; r < 4; ++r)
            h_last[(long)(r0 + mt * 16 + q * 4 + r) * HDIM + w * 16 + c] = h_reg[mt][r];
}

// ---------------- K3: segmented softmax attention + output GEMMs (fp32 out) -
__global__ __launch_bounds__(64) void k3_attn(
    const float* __restrict__ h_last, const int* __restrict__ seg,
    const float* __restrict__ attn, const float* __restrict__ Wout,
    const float* __restrict__ Wcls, float* __restrict__ out)
{
    __shared__ float code_s[128];
    const int g = blockIdx.x, l = threadIdx.x;

    int lo, hi;
    { int a = 0, b = NPATH; while (a < b) { int m = (a + b) >> 1; if (seg[m] < g) a = m + 1; else b = m; } lo = a; }
    { int a = lo, b = NPATH; while (a < b) { int m = (a + b) >> 1; if (seg[m] < g + 1) a = m + 1; else b = m; } hi = a; }

    float a0 = attn[l], a1 = attn[l + 64];
    float mrun = -1e30f, Z = 0.f;
    for (int n = lo; n < hi; ++n) {        // online softmax stats
        const float* hr = &h_last[(long)n * HDIM];
        float v = hr[l] * a0 + hr[l + 64] * a1;
        #pragma unroll
        for (int m = 1; m < 64; m <<= 1) v += __shfl_xor(v, m, 64);
        float nm = fmaxf(mrun, v);
        Z = Z * __expf(mrun - nm) + __expf(v - nm);
        mrun = nm;
    }
    float w0 = 0.f, w1 = 0.f;
    for (int n = lo; n < hi; ++n) {        // weighted sum
        const float* hr = &h_last[(long)n * HDIM];
        float v = hr[l] * a0 + hr[l + 64] * a1;
        #pragma unroll
        for (int m = 1; m < 64; m <<= 1) v += __shfl_xor(v, m, 64);
        float at = __expf(v - mrun) / Z;
        w0 += at * hr[l]; w1 += at * hr[l + 64];
    }
    float inv_cnt = (hi > lo) ? 1.f / (float)(hi - lo) : 0.f;
    code_s[l] = w0 * inv_cnt; code_s[l + 64] = w1 * inv_cnt;
    __syncthreads();

    float cv0 = 0.f, cv1 = 0.f;            // code @ W_out.T
    for (int k = 0; k < 128; ++k) {
        float ck = code_s[k];
        cv0 += ck * Wout[l * 128 + k];
        cv1 += ck * Wout[(l + 64) * 128 + k];
    }
    out[2048 + g * 128 + l]      = cv0;
    out[2048 + g * 128 + l + 64] = cv1;

    float p0 = cv0 * Wcls[l] + cv1 * Wcls[l + 64];          // cv @ W_cls.T
    float p1 = cv0 * Wcls[128 + l] + cv1 * Wcls[128 + l + 64];
    #pragma unroll
    for (int m = 1; m < 64; m <<= 1) { p0 += __shfl_xor(p0, m, 64); p1 += __shfl_xor(p1, m, 64); }
    if (l == 0) { out[g * 2 + 0] = p0; out[g * 2 + 1] = p1; }
    if (g == 0) { out[133120 + l] = attn[l]; out[133120 + 64 + l] = attn[l + 64]; }
}

extern "C" void kernel_launch(void* const* d_in, const int* in_sizes, int n_in,
                              void* d_out, int out_size, void* d_ws, size_t ws_size,
                              hipStream_t stream) {
    const float* inp  = (const float*)d_in[0];
    const int*   lens = (const int*)d_in[1];
    const int*   seg  = (const int*)d_in[2];
    const float* Win  = (const float*)d_in[3];
    const float* gam  = (const float*)d_in[4];
    const float* bet  = (const float*)d_in[5];
    const float* Wih  = (const float*)d_in[6];
    const float* Whh  = (const float*)d_in[7];
    const float* bih  = (const float*)d_in[8];
    const float* bhh  = (const float*)d_in[9];
    const float* attn = (const float*)d_in[10];
    const float* Wout = (const float*)d_in[11];
    const float* Wcls = (const float*)d_in[12];

    unsigned short* xt = (unsigned short*)d_ws;                               // 64 MB bf16 x~
    float* h_last = (float*)((char*)d_ws + (size_t)NTOK * EDIM * 2);          // 4 MB f32

    hipLaunchKernelGGL(k1_proj, dim3(NTOK / K1_ROWS), dim3(512), 0, stream, inp, Win, gam, bet, xt);
    hipLaunchKernelGGL(k2_lstm, dim3(NPATH / 32), dim3(512), 0, stream, xt, Wih, Whh, bih, bhh, lens, h_last);
    hipLaunchKernelGGL(k3_attn, dim3(NGRP), dim3(64), 0, stream, h_last, seg, attn, Wout, Wcls,
                       (float*)d_out);
}